// Round 1
// baseline (168.190 us; speedup 1.0000x reference)
//
#include <hip/hip_runtime.h>
#include <math.h>

// Problem constants (from reference setup_inputs)
#define BN 16        // batch
#define BC 256       // channels
#define BK 8         // kernel size k
#define BM 63        // input spatial m
#define MO 56        // output spatial m-k+1
#define KK (BK*BK)   // 64

// Parallelization
#define CH_PER_BLOCK 8
#define NCHUNK (BC / CH_PER_BLOCK)   // 32 -> grid 16x32 = 512 blocks (~2/CU)
#define TX_N 8                        // thread grid: 8 cols x 28 rows
#define TY_N 28
#define NTHREADS (TX_N * TY_N)        // 224 threads (3.5 waves)
#define TILE_H 2                      // per-thread output tile 2x7 -> exact 56x56
#define TILE_W 7
#define WIN_H (TILE_H + BK - 1)       // 9
#define WIN_W (TILE_W + BK - 1)       // 14
#define XS_STRIDE 65                  // 63 cols padded to 65: ~2-way banks (free)

__global__ __launch_bounds__(NTHREADS, 2)
void bhat_kernel(const float* __restrict__ z,
                 const float* __restrict__ x,
                 const float* __restrict__ w,
                 float* __restrict__ out) {
    __shared__ float xs[BM * XS_STRIDE];          // 63*65*4 = 16.4 KB
    __shared__ float zs[CH_PER_BLOCK * KK];       // 8*64*4  = 2 KB

    const int n     = blockIdx.x;                 // sample
    const int c0    = blockIdx.y * CH_PER_BLOCK;  // channel chunk base
    const int tid   = threadIdx.x;
    const int TX    = tid & (TX_N - 1);
    const int TY    = tid >> 3;
    const int row0  = TY * TILE_H;                // output tile origin
    const int col0  = TX * TILE_W;

    // Stage w[c]*sqrt(z) for this chunk once.
    {
        const float* zbase = z + ((size_t)n * BC + c0) * KK;
        for (int i = tid; i < CH_PER_BLOCK * KK; i += NTHREADS) {
            int ci = i >> 6;                      // /64
            zs[i] = w[c0 + ci] * sqrtf(zbase[i]);
        }
    }

    float acc[TILE_H][TILE_W];
#pragma unroll
    for (int a = 0; a < TILE_H; ++a)
#pragma unroll
        for (int b = 0; b < TILE_W; ++b) acc[a][b] = 0.0f;

    for (int ci = 0; ci < CH_PER_BLOCK; ++ci) {
        const float* xbase = x + ((size_t)n * BC + c0 + ci) * (BM * BM);

        __syncthreads();   // xs readers from previous iter done (also fences zs stage on iter 0 via the barrier below)
        // Stage sqrt(x[n,c]) into LDS, coalesced flat reads.
        for (int i = tid; i < BM * BM; i += NTHREADS) {
            int r = i / BM;
            int c = i - r * BM;
            xs[r * XS_STRIDE + c] = sqrtf(xbase[i]);
        }
        __syncthreads();

        // Register-cache the 9x14 window this thread needs.
        float xr[WIN_H][WIN_W];
#pragma unroll
        for (int r = 0; r < WIN_H; ++r)
#pragma unroll
            for (int c = 0; c < WIN_W; ++c)
                xr[r][c] = xs[(row0 + r) * XS_STRIDE + col0 + c];

        const float* zrow = &zs[ci * KK];
#pragma unroll
        for (int p = 0; p < BK; ++p)
#pragma unroll
            for (int q = 0; q < BK; ++q) {
                const float zv = zrow[p * BK + q];   // uniform addr -> broadcast
#pragma unroll
                for (int a = 0; a < TILE_H; ++a)
#pragma unroll
                    for (int b = 0; b < TILE_W; ++b)
                        acc[a][b] = fmaf(xr[a + p][b + q], zv, acc[a][b]);
            }
    }

    // Epilogue: scale by 1/k^2, accumulate across channel chunks.
    const float scale = 1.0f / (float)KK;
    float* obase = out + (size_t)n * (MO * MO);
#pragma unroll
    for (int a = 0; a < TILE_H; ++a)
#pragma unroll
        for (int b = 0; b < TILE_W; ++b)
            atomicAdd(&obase[(row0 + a) * MO + col0 + b], acc[a][b] * scale);
}

extern "C" void kernel_launch(void* const* d_in, const int* in_sizes, int n_in,
                              void* d_out, int out_size, void* d_ws, size_t ws_size,
                              hipStream_t stream) {
    const float* z = (const float*)d_in[0];   // (16,256,8,8)
    const float* x = (const float*)d_in[1];   // (16,256,63,63)
    const float* w = (const float*)d_in[2];   // (1,256,1,1,1) -> 256
    float* out = (float*)d_out;               // (16,1,56,56) = 50176 floats

    // d_out is re-poisoned before every launch; we accumulate with atomics.
    hipMemsetAsync(out, 0, (size_t)out_size * sizeof(float), stream);

    dim3 grid(BN, NCHUNK);
    bhat_kernel<<<grid, NTHREADS, 0, stream>>>(z, x, w, out);
}